// Round 12
// baseline (159.880 us; speedup 1.0000x reference)
//
#include <hip/hip_runtime.h>

#define IN_F 256
#define OUT_F 128
#define BSH 7
#define BNODES 128          // nodes per bucket = 1<<BSH
#define MAXBUCK 1024        // supports n_nodes <= 131072
#define BIN1A_BLOCKS 256
#define BIN1B_BLOCKS 256

typedef short bf16x8 __attribute__((ext_vector_type(8)));
typedef float f32x4 __attribute__((ext_vector_type(4)));

__device__ inline unsigned short f2bf(float x) {
    union { float f; unsigned u; } v; v.f = x;
    unsigned r = v.u + 0x7FFFu + ((v.u >> 16) & 1u);   // round-nearest-even
    return (unsigned short)(r >> 16);
}
__device__ inline float bf2f(unsigned short x) {
    union { unsigned u; float f; } v; v.u = ((unsigned)x) << 16;
    return v.f;
}

// ---------------------------------------------------------------------------
// K1 fused: blocks [0, BIN1A_BLOCKS) = bin1a; blocks [BIN1A_BLOCKS,+128) = wprep.
// ---------------------------------------------------------------------------
__global__ __launch_bounds__(256) void prep_kernel(const float* __restrict__ W,
                                                   unsigned short* __restrict__ Wt,
                                                   const int* __restrict__ dst,
                                                   int* __restrict__ bhist,
                                                   int n_edges, int nbuck) {
    if ((int)blockIdx.x < BIN1A_BLOCKS) {
        __shared__ int hist[MAXBUCK];
        const int tid = threadIdx.x;
        const int chunk = (n_edges + BIN1A_BLOCKS - 1) / BIN1A_BLOCKS;
        const int lo = blockIdx.x * chunk;
        const int hi = min(lo + chunk, n_edges);

        for (int i = tid; i < MAXBUCK; i += 256) hist[i] = 0;
        __syncthreads();
        for (int e = lo + tid; e < hi; e += 256)
            atomicAdd(&hist[dst[e] >> BSH], 1);
        __syncthreads();
        for (int i = tid; i < nbuck; i += 256) {
            int c = hist[i];
            if (c) atomicAdd(&bhist[i], c);
        }
    } else {
        int n = blockIdx.x - BIN1A_BLOCKS;   // 0..127
        int k = threadIdx.x;                 // 0..255
        Wt[n * IN_F + k] = f2bf(W[k * OUT_F + n]);
    }
}

// ---------------------------------------------------------------------------
// scanb: single-block exclusive scan over bucket counts -> bstart, gcur.
// ---------------------------------------------------------------------------
__global__ __launch_bounds__(1024) void scanb_kernel(const int* __restrict__ bhist,
                                                     int* __restrict__ bstart,
                                                     int* __restrict__ gcur,
                                                     int* __restrict__ rstart,
                                                     int nbuck, int n_nodes) {
    __shared__ int sh[1024];
    int tid = threadIdx.x;
    int v = (tid < nbuck) ? bhist[tid] : 0;
    sh[tid] = v;
    __syncthreads();
    #pragma unroll
    for (int off = 1; off < 1024; off <<= 1) {
        int t = (tid >= off) ? sh[tid - off] : 0;
        __syncthreads();
        sh[tid] += t;
        __syncthreads();
    }
    int ex = sh[tid] - v;
    if (tid < nbuck) { bstart[tid] = ex; gcur[tid] = ex; }
    if (tid == 1023) {
        bstart[nbuck] = sh[1023];
        rstart[n_nodes] = sh[1023];   // sentinel (== n_edges)
    }
}

// ---------------------------------------------------------------------------
// bin1b (standalone again — fusing with 64KB-LDS gemm blocks hoarded CU slots):
// two-pass LDS-histogram binning into bucket-grouped ebuf.
// ---------------------------------------------------------------------------
__global__ __launch_bounds__(256) void bin1b_kernel(const int* __restrict__ src,
                                                    const int* __restrict__ dst,
                                                    int* __restrict__ gcur,
                                                    unsigned* __restrict__ ebuf,
                                                    int n_edges, int nbuck) {
    __shared__ int hist[MAXBUCK];
    __shared__ int lbase[MAXBUCK];
    const int tid = threadIdx.x;
    const int chunk = (n_edges + BIN1B_BLOCKS - 1) / BIN1B_BLOCKS;
    const int lo = blockIdx.x * chunk;
    const int hi = min(lo + chunk, n_edges);

    for (int i = tid; i < nbuck; i += 256) hist[i] = 0;
    __syncthreads();
    for (int e = lo + tid; e < hi; e += 256)
        atomicAdd(&hist[dst[e] >> BSH], 1);
    __syncthreads();
    for (int i = tid; i < nbuck; i += 256) {
        int c = hist[i];
        lbase[i] = (c > 0) ? atomicAdd(&gcur[i], c) : 0;
        hist[i] = 0;            // reuse as local cursor
    }
    __syncthreads();
    for (int e = lo + tid; e < hi; e += 256) {
        int d = dst[e];
        int bkt = d >> BSH;
        int off = atomicAdd(&hist[bkt], 1);
        ebuf[lbase[bkt] + off] = ((unsigned)src[e] << BSH) | (unsigned)(d & (BNODES - 1));
    }
}

// ---------------------------------------------------------------------------
// gemm: h = bf16( feat @ W ). 1024 threads = 16 waves x 16 rows = 256 rows/blk.
// 64 KB swizzled Wt in LDS (staged once per block); 2 blocks/CU -> 32 waves/CU
// = 8 waves/SIMD (was 4): doubles the TLP that hides the A-load HBM latency,
// which the VGPR=52 counter proved the compiler won't hide via ILP.
// ---------------------------------------------------------------------------
__global__ __launch_bounds__(1024) void gemm_mfma(const float* __restrict__ feat,
                                                  const unsigned short* __restrict__ Wt,
                                                  unsigned short* __restrict__ h,
                                                  int n_nodes) {
    __shared__ unsigned short Bs[OUT_F * IN_F];   // 64 KB, swizzled

    const int tid  = threadIdx.x;
    const int wave = tid >> 6;           // 0..15
    const int lane = tid & 63;
    const int r0   = (blockIdx.x * 16 + wave) * 16;
    const int lrow = lane & 15;
    const int g    = lane >> 4;          // k-group 0..3
    const int kgrp = g * 8;

    // stage Wt -> LDS (swizzled): 4096 x 16B chunks, 4 per thread
    {
        const f32x4* srcv = reinterpret_cast<const f32x4*>(Wt);
        f32x4* dstv = reinterpret_cast<f32x4*>(Bs);
        #pragma unroll
        for (int i = 0; i < 4; ++i) {
            int c   = tid + i * 1024;       // 16B-chunk index 0..4095
            int row = c >> 5;               // 0..127
            int col = c & 31;               // 16B unit within row
            dstv[c] = srcv[row * 32 + (col ^ (row & 7))];
        }
    }

    const int row  = r0 + lrow;
    const int rowc = (row < n_nodes) ? row : (n_nodes - 1);
    const float* arow = feat + (size_t)rowc * IN_F;

    __syncthreads();   // Bs ready

    f32x4 acc[8];
    #pragma unroll
    for (int n = 0; n < 8; ++n) acc[n] = (f32x4){0.f, 0.f, 0.f, 0.f};

    const bf16x8* bsv = reinterpret_cast<const bf16x8*>(Bs);

    #pragma unroll
    for (int k0 = 0; k0 < IN_F / 32; ++k0) {
        const f32x4 a0 = *reinterpret_cast<const f32x4*>(arow + k0 * 32 + kgrp);
        const f32x4 a1 = *reinterpret_cast<const f32x4*>(arow + k0 * 32 + kgrp + 4);
        bf16x8 afr;
        afr[0] = (short)f2bf(a0[0]);
        afr[1] = (short)f2bf(a0[1]);
        afr[2] = (short)f2bf(a0[2]);
        afr[3] = (short)f2bf(a0[3]);
        afr[4] = (short)f2bf(a1[0]);
        afr[5] = (short)f2bf(a1[1]);
        afr[6] = (short)f2bf(a1[2]);
        afr[7] = (short)f2bf(a1[3]);
        #pragma unroll
        for (int n = 0; n < 8; ++n) {
            const int brow = n * 16 + lrow;
            bf16x8 bfr = bsv[brow * 32 + ((k0 * 4 + g) ^ (brow & 7))];
            acc[n] = __builtin_amdgcn_mfma_f32_16x16x32_bf16(afr, bfr, acc[n], 0, 0, 0);
        }
    }

    const int orow0 = r0 + g * 4;
    #pragma unroll
    for (int n = 0; n < 8; ++n) {
        #pragma unroll
        for (int j = 0; j < 4; ++j) {
            int orow = orow0 + j;
            if (orow < n_nodes)
                h[(size_t)orow * OUT_F + n * 16 + lrow] = f2bf(acc[n][j]);
        }
    }
}

// ---------------------------------------------------------------------------
// bin2: one block per bucket -> exact per-node CSR + norm. Bucket-local writes.
// ---------------------------------------------------------------------------
__global__ __launch_bounds__(256) void bin2_kernel(const unsigned* __restrict__ ebuf,
                                                   const int* __restrict__ bstart,
                                                   int* __restrict__ rstart,
                                                   float* __restrict__ norm,
                                                   int* __restrict__ eidx,
                                                   int n_nodes) {
    __shared__ int lcnt[BNODES];
    __shared__ int lex[BNODES];
    const int tid = threadIdx.x;
    const int node0 = blockIdx.x << BSH;
    const int e0 = bstart[blockIdx.x];
    const int e1 = bstart[blockIdx.x + 1];

    if (tid < BNODES) lcnt[tid] = 0;
    __syncthreads();
    for (int e = e0 + tid; e < e1; e += 256)
        atomicAdd(&lcnt[ebuf[e] & (BNODES - 1)], 1);
    __syncthreads();

    int own = (tid < BNODES) ? lcnt[tid] : 0;
    if (tid < BNODES) lex[tid] = own;
    __syncthreads();
    #pragma unroll
    for (int off = 1; off < BNODES; off <<= 1) {
        int t = (tid >= off && tid < BNODES) ? lex[tid - off] : 0;
        __syncthreads();
        if (tid < BNODES) lex[tid] += t;
        __syncthreads();
    }
    if (tid < BNODES) {
        int ex = lex[tid] - own;       // exclusive
        lex[tid] = ex;
        int g = node0 + tid;
        if (g <= n_nodes) rstart[g] = e0 + ex;
        if (g < n_nodes) {
            float d = (float)own;
            if (d < 1.0f) d = 1.0f;
            norm[g] = 1.0f / sqrtf(d);
        }
        lcnt[tid] = 0;                 // reuse as cursor
    }
    __syncthreads();

    for (int e = e0 + tid; e < e1; e += 256) {
        unsigned pk = ebuf[e];
        int dl = pk & (BNODES - 1);
        int pos = atomicAdd(&lcnt[dl], 1);
        eidx[e0 + lex[dl] + pos] = (int)(pk >> BSH);
    }
}

// ---------------------------------------------------------------------------
// agg: one wave per dst node. Per 64-edge chunk: eidx + norm[src] loaded
// lane-parallel ONCE, distributed via shfl; h-row gathers 8-deep in flight.
// ---------------------------------------------------------------------------
__global__ __launch_bounds__(256) void agg_kernel(const unsigned short* __restrict__ h,
                                                  const int* __restrict__ eidx,
                                                  const int* __restrict__ rstart,
                                                  const float* __restrict__ norm,
                                                  const float* __restrict__ bias,
                                                  float* __restrict__ out,
                                                  int n_nodes) {
    const int wave = threadIdx.x >> 6;
    const int lane = threadIdx.x & 63;
    const int node = blockIdx.x * 4 + wave;
    if (node >= n_nodes) return;

    const int start = rstart[node];
    const int cnt   = rstart[node + 1] - start;

    float a0 = 0.f, a1 = 0.f;
    for (int base = 0; base < cnt; base += 64) {
        const int rem = min(64, cnt - base);
        int   ev = (lane < rem) ? eidx[start + base + lane] : 0;
        float nv = (lane < rem) ? norm[ev] : 0.f;

        int j = 0;
        for (; j + 8 <= rem; j += 8) {
            unsigned v[8];
            float    nn[8];
            #pragma unroll
            for (int q = 0; q < 8; ++q) {
                int s = __shfl(ev, j + q);
                nn[q] = __shfl(nv, j + q);
                v[q]  = *reinterpret_cast<const unsigned*>(h + (size_t)s * OUT_F + lane * 2);
            }
            #pragma unroll
            for (int q = 0; q < 8; ++q) {
                a0 += bf2f((unsigned short)(v[q] & 0xffffu)) * nn[q];
                a1 += bf2f((unsigned short)(v[q] >> 16))     * nn[q];
            }
        }
        for (; j < rem; ++j) {
            int   s  = __shfl(ev, j);
            float nm = __shfl(nv, j);
            unsigned v = *reinterpret_cast<const unsigned*>(h + (size_t)s * OUT_F + lane * 2);
            a0 += bf2f((unsigned short)(v & 0xffffu)) * nm;
            a1 += bf2f((unsigned short)(v >> 16))     * nm;
        }
    }

    const float nd = norm[node];
    float2 r;
    r.x = a0 * nd + bias[lane * 2];
    r.y = a1 * nd + bias[lane * 2 + 1];
    *reinterpret_cast<float2*>(out + (size_t)node * OUT_F + lane * 2) = r;
}

// ---------------------------------------------------------------------------
extern "C" void kernel_launch(void* const* d_in, const int* in_sizes, int n_in,
                              void* d_out, int out_size, void* d_ws, size_t ws_size,
                              hipStream_t stream) {
    const float* feat   = (const float*)d_in[0];
    const float* weight = (const float*)d_in[1];
    const float* bias   = (const float*)d_in[2];
    const int*   src    = (const int*)d_in[3];
    const int*   dst    = (const int*)d_in[4];
    float* out = (float*)d_out;

    const int n_nodes = in_sizes[0] / IN_F;
    const int n_edges = in_sizes[3];
    const int nbuck   = (n_nodes + BNODES - 1) >> BSH;
    const int gemm_blocks = (n_nodes + 255) / 256;

    char* ws = (char*)d_ws;
    size_t off = 0;
    auto alloc = [&](size_t bytes) {
        char* p = ws + off;
        off += (bytes + 15) & ~(size_t)15;
        return p;
    };
    unsigned short* h  = (unsigned short*)alloc((size_t)n_nodes * OUT_F * 2);
    float* norm        = (float*)alloc((size_t)n_nodes * 4);
    int*   rstart      = (int*)alloc(((size_t)n_nodes + 1) * 4);
    int*   bhist       = (int*)alloc(MAXBUCK * 4);
    int*   bstart      = (int*)alloc((MAXBUCK + 1) * 4);
    int*   gcur        = (int*)alloc(MAXBUCK * 4);
    unsigned short* Wt = (unsigned short*)alloc((size_t)OUT_F * IN_F * 2);
    unsigned* ebuf     = (unsigned*)alloc((size_t)n_edges * 4);
    int*   eidx        = (int*)alloc((size_t)n_edges * 4);

    hipMemsetAsync(bhist, 0, MAXBUCK * sizeof(int), stream);
    // K1: bin1a (blocks 0..255) || wprep (blocks 256..383)
    prep_kernel<<<BIN1A_BLOCKS + OUT_F, 256, 0, stream>>>(weight, Wt, dst, bhist,
                                                          n_edges, nbuck);
    // K2: bucket scan
    scanb_kernel<<<1, 1024, 0, stream>>>(bhist, bstart, gcur, rstart, nbuck, n_nodes);
    // K3: binning
    bin1b_kernel<<<BIN1B_BLOCKS, 256, 0, stream>>>(src, dst, gcur, ebuf, n_edges, nbuck);
    // K4: gemm (independent of bin chain; needs only Wt)
    gemm_mfma<<<gemm_blocks, 1024, 0, stream>>>(feat, Wt, h, n_nodes);
    // K5: exact CSR
    bin2_kernel<<<nbuck, 256, 0, stream>>>(ebuf, bstart, rstart, norm, eidx, n_nodes);
    // K6: aggregate
    agg_kernel<<<(n_nodes + 3) / 4, 256, 0, stream>>>(h, eidx, rstart, norm, bias, out, n_nodes);
}

// Round 14
// 156.246 us; speedup vs baseline: 1.0233x; 1.0233x over previous
//
#include <hip/hip_runtime.h>

#define IN_F 256
#define OUT_F 128
#define BSH 7
#define BNODES 128          // nodes per bucket = 1<<BSH
#define MAXBUCK 1024        // supports n_nodes <= 131072
#define BIN1A_BLOCKS 256
#define BIN1B_BLOCKS 256

typedef short bf16x8 __attribute__((ext_vector_type(8)));
typedef float f32x4 __attribute__((ext_vector_type(4)));
typedef unsigned short us8 __attribute__((ext_vector_type(8)));

__device__ inline unsigned short f2bf(float x) {
    union { float f; unsigned u; } v; v.f = x;
    unsigned r = v.u + 0x7FFFu + ((v.u >> 16) & 1u);   // round-nearest-even
    return (unsigned short)(r >> 16);
}
__device__ inline float bf2f(unsigned short x) {
    union { unsigned u; float f; } v; v.u = ((unsigned)x) << 16;
    return v.f;
}

// ---------------------------------------------------------------------------
// K1 fused: blocks [0, BIN1A_BLOCKS) = bin1a; blocks [BIN1A_BLOCKS,+128) = wprep.
// ---------------------------------------------------------------------------
__global__ __launch_bounds__(256) void prep_kernel(const float* __restrict__ W,
                                                   unsigned short* __restrict__ Wt,
                                                   const int* __restrict__ dst,
                                                   int* __restrict__ bhist,
                                                   int n_edges, int nbuck) {
    if ((int)blockIdx.x < BIN1A_BLOCKS) {
        __shared__ int hist[MAXBUCK];
        const int tid = threadIdx.x;
        const int chunk = (n_edges + BIN1A_BLOCKS - 1) / BIN1A_BLOCKS;
        const int lo = blockIdx.x * chunk;
        const int hi = min(lo + chunk, n_edges);

        for (int i = tid; i < MAXBUCK; i += 256) hist[i] = 0;
        __syncthreads();
        for (int e = lo + tid; e < hi; e += 256)
            atomicAdd(&hist[dst[e] >> BSH], 1);
        __syncthreads();
        for (int i = tid; i < nbuck; i += 256) {
            int c = hist[i];
            if (c) atomicAdd(&bhist[i], c);
        }
    } else {
        int n = blockIdx.x - BIN1A_BLOCKS;   // 0..127
        int k = threadIdx.x;                 // 0..255
        Wt[n * IN_F + k] = f2bf(W[k * OUT_F + n]);
    }
}

// ---------------------------------------------------------------------------
// scanb: single-block exclusive scan over bucket counts -> bstart, gcur.
// ---------------------------------------------------------------------------
__global__ __launch_bounds__(1024) void scanb_kernel(const int* __restrict__ bhist,
                                                     int* __restrict__ bstart,
                                                     int* __restrict__ gcur,
                                                     int* __restrict__ rstart,
                                                     int nbuck, int n_nodes) {
    __shared__ int sh[1024];
    int tid = threadIdx.x;
    int v = (tid < nbuck) ? bhist[tid] : 0;
    sh[tid] = v;
    __syncthreads();
    #pragma unroll
    for (int off = 1; off < 1024; off <<= 1) {
        int t = (tid >= off) ? sh[tid - off] : 0;
        __syncthreads();
        sh[tid] += t;
        __syncthreads();
    }
    int ex = sh[tid] - v;
    if (tid < nbuck) { bstart[tid] = ex; gcur[tid] = ex; }
    if (tid == 1023) {
        bstart[nbuck] = sh[1023];
        rstart[n_nodes] = sh[1023];   // sentinel (== n_edges)
    }
}

// ---------------------------------------------------------------------------
// bin1b: two-pass LDS-histogram binning into bucket-grouped ebuf.
// ---------------------------------------------------------------------------
__global__ __launch_bounds__(256) void bin1b_kernel(const int* __restrict__ src,
                                                    const int* __restrict__ dst,
                                                    int* __restrict__ gcur,
                                                    unsigned* __restrict__ ebuf,
                                                    int n_edges, int nbuck) {
    __shared__ int hist[MAXBUCK];
    __shared__ int lbase[MAXBUCK];
    const int tid = threadIdx.x;
    const int chunk = (n_edges + BIN1B_BLOCKS - 1) / BIN1B_BLOCKS;
    const int lo = blockIdx.x * chunk;
    const int hi = min(lo + chunk, n_edges);

    for (int i = tid; i < nbuck; i += 256) hist[i] = 0;
    __syncthreads();
    for (int e = lo + tid; e < hi; e += 256)
        atomicAdd(&hist[dst[e] >> BSH], 1);
    __syncthreads();
    for (int i = tid; i < nbuck; i += 256) {
        int c = hist[i];
        lbase[i] = (c > 0) ? atomicAdd(&gcur[i], c) : 0;
        hist[i] = 0;            // reuse as local cursor
    }
    __syncthreads();
    for (int e = lo + tid; e < hi; e += 256) {
        int d = dst[e];
        int bkt = d >> BSH;
        int off = atomicAdd(&hist[bkt], 1);
        ebuf[lbase[bkt] + off] = ((unsigned)src[e] << BSH) | (unsigned)(d & (BNODES - 1));
    }
}

// ---------------------------------------------------------------------------
// gemm: h = bf16( feat @ W ). 1024 threads = 16 waves x 16 rows = 256 rows/blk.
// 64 KB swizzled Wt in LDS; 2 blocks/CU -> 32 waves/CU = 8 waves/SIMD.
// ---------------------------------------------------------------------------
__global__ __launch_bounds__(1024) void gemm_mfma(const float* __restrict__ feat,
                                                  const unsigned short* __restrict__ Wt,
                                                  unsigned short* __restrict__ h,
                                                  int n_nodes) {
    __shared__ unsigned short Bs[OUT_F * IN_F];   // 64 KB, swizzled

    const int tid  = threadIdx.x;
    const int wave = tid >> 6;           // 0..15
    const int lane = tid & 63;
    const int r0   = (blockIdx.x * 16 + wave) * 16;
    const int lrow = lane & 15;
    const int g    = lane >> 4;          // k-group 0..3
    const int kgrp = g * 8;

    // stage Wt -> LDS (swizzled): 4096 x 16B chunks, 4 per thread
    {
        const f32x4* srcv = reinterpret_cast<const f32x4*>(Wt);
        f32x4* dstv = reinterpret_cast<f32x4*>(Bs);
        #pragma unroll
        for (int i = 0; i < 4; ++i) {
            int c   = tid + i * 1024;       // 16B-chunk index 0..4095
            int row = c >> 5;               // 0..127
            int col = c & 31;               // 16B unit within row
            dstv[c] = srcv[row * 32 + (col ^ (row & 7))];
        }
    }

    const int row  = r0 + lrow;
    const int rowc = (row < n_nodes) ? row : (n_nodes - 1);
    const float* arow = feat + (size_t)rowc * IN_F;

    __syncthreads();   // Bs ready

    f32x4 acc[8];
    #pragma unroll
    for (int n = 0; n < 8; ++n) acc[n] = (f32x4){0.f, 0.f, 0.f, 0.f};

    const bf16x8* bsv = reinterpret_cast<const bf16x8*>(Bs);

    #pragma unroll
    for (int k0 = 0; k0 < IN_F / 32; ++k0) {
        const f32x4 a0 = *reinterpret_cast<const f32x4*>(arow + k0 * 32 + kgrp);
        const f32x4 a1 = *reinterpret_cast<const f32x4*>(arow + k0 * 32 + kgrp + 4);
        bf16x8 afr;
        afr[0] = (short)f2bf(a0[0]);
        afr[1] = (short)f2bf(a0[1]);
        afr[2] = (short)f2bf(a0[2]);
        afr[3] = (short)f2bf(a0[3]);
        afr[4] = (short)f2bf(a1[0]);
        afr[5] = (short)f2bf(a1[1]);
        afr[6] = (short)f2bf(a1[2]);
        afr[7] = (short)f2bf(a1[3]);
        #pragma unroll
        for (int n = 0; n < 8; ++n) {
            const int brow = n * 16 + lrow;
            bf16x8 bfr = bsv[brow * 32 + ((k0 * 4 + g) ^ (brow & 7))];
            acc[n] = __builtin_amdgcn_mfma_f32_16x16x32_bf16(afr, bfr, acc[n], 0, 0, 0);
        }
    }

    const int orow0 = r0 + g * 4;
    #pragma unroll
    for (int n = 0; n < 8; ++n) {
        #pragma unroll
        for (int j = 0; j < 4; ++j) {
            int orow = orow0 + j;
            if (orow < n_nodes)
                h[(size_t)orow * OUT_F + n * 16 + lrow] = f2bf(acc[n][j]);
        }
    }
}

// ---------------------------------------------------------------------------
// bin2: one block per bucket -> exact per-node CSR + norm. Bucket-local writes.
// ---------------------------------------------------------------------------
__global__ __launch_bounds__(256) void bin2_kernel(const unsigned* __restrict__ ebuf,
                                                   const int* __restrict__ bstart,
                                                   int* __restrict__ rstart,
                                                   float* __restrict__ norm,
                                                   int* __restrict__ eidx,
                                                   int n_nodes) {
    __shared__ int lcnt[BNODES];
    __shared__ int lex[BNODES];
    const int tid = threadIdx.x;
    const int node0 = blockIdx.x << BSH;
    const int e0 = bstart[blockIdx.x];
    const int e1 = bstart[blockIdx.x + 1];

    if (tid < BNODES) lcnt[tid] = 0;
    __syncthreads();
    for (int e = e0 + tid; e < e1; e += 256)
        atomicAdd(&lcnt[ebuf[e] & (BNODES - 1)], 1);
    __syncthreads();

    int own = (tid < BNODES) ? lcnt[tid] : 0;
    if (tid < BNODES) lex[tid] = own;
    __syncthreads();
    #pragma unroll
    for (int off = 1; off < BNODES; off <<= 1) {
        int t = (tid >= off && tid < BNODES) ? lex[tid - off] : 0;
        __syncthreads();
        if (tid < BNODES) lex[tid] += t;
        __syncthreads();
    }
    if (tid < BNODES) {
        int ex = lex[tid] - own;       // exclusive
        lex[tid] = ex;
        int g = node0 + tid;
        if (g <= n_nodes) rstart[g] = e0 + ex;
        if (g < n_nodes) {
            float d = (float)own;
            if (d < 1.0f) d = 1.0f;
            norm[g] = 1.0f / sqrtf(d);
        }
        lcnt[tid] = 0;                 // reuse as cursor
    }
    __syncthreads();

    for (int e = e0 + tid; e < e1; e += 256) {
        unsigned pk = ebuf[e];
        int dl = pk & (BNODES - 1);
        int pos = atomicAdd(&lcnt[dl], 1);
        eidx[e0 + lex[dl] + pos] = (int)(pk >> BSH);
    }
}

// ---------------------------------------------------------------------------
// agg: one wave per dst node, 4 edge-slots x 16 lanes, UNIFORM control flow.
// All lanes iterate the same j (0,16,32..); in each main iteration the wave
// covers edges j..j+15: group g (lane>>4) takes edges j+g, j+g+4, j+g+8,
// j+g+12 (all < rem since j+16 <= rem). Each lane loads 16 B (8 feats) of
// its edge's h row -> one dwordx4 covers 4 edges per wave-instruction.
// Tail steps j+=4 uniformly with DATA predication (clamped shfl index,
// nm=0 for out-of-range) — divergence only in selects, never around shfl.
// Epilogue: butterfly shfl_xor(16,32) combines the 4 groups; group 0 writes.
// ---------------------------------------------------------------------------
__global__ __launch_bounds__(256) void agg_kernel(const unsigned short* __restrict__ h,
                                                  const int* __restrict__ eidx,
                                                  const int* __restrict__ rstart,
                                                  const float* __restrict__ norm,
                                                  const float* __restrict__ bias,
                                                  float* __restrict__ out,
                                                  int n_nodes) {
    const int wave = threadIdx.x >> 6;
    const int lane = threadIdx.x & 63;
    const int grp  = lane >> 4;          // edge slot 0..3
    const int gl   = lane & 15;          // feature chunk
    const int node = blockIdx.x * 4 + wave;
    if (node >= n_nodes) return;         // wave-uniform; no barriers below

    const int start = rstart[node];
    const int cnt   = rstart[node + 1] - start;
    const unsigned short* __restrict__ hb = h + gl * 8;

    float acc[8] = {0.f, 0.f, 0.f, 0.f, 0.f, 0.f, 0.f, 0.f};

    for (int base = 0; base < cnt; base += 64) {
        const int rem = min(64, cnt - base);     // wave-uniform
        int   ev = (lane < rem) ? eidx[start + base + lane] : 0;
        float nv = (lane < rem) ? norm[ev] : 0.f;

        int j = 0;
        for (; j + 16 <= rem; j += 16) {         // uniform bound
            int   s0 = __shfl(ev, j + grp);
            int   s1 = __shfl(ev, j + grp + 4);
            int   s2 = __shfl(ev, j + grp + 8);
            int   s3 = __shfl(ev, j + grp + 12);
            float n0 = __shfl(nv, j + grp);
            float n1 = __shfl(nv, j + grp + 4);
            float n2 = __shfl(nv, j + grp + 8);
            float n3 = __shfl(nv, j + grp + 12);
            us8 v0 = *reinterpret_cast<const us8*>(hb + (size_t)s0 * OUT_F);
            us8 v1 = *reinterpret_cast<const us8*>(hb + (size_t)s1 * OUT_F);
            us8 v2 = *reinterpret_cast<const us8*>(hb + (size_t)s2 * OUT_F);
            us8 v3 = *reinterpret_cast<const us8*>(hb + (size_t)s3 * OUT_F);
            #pragma unroll
            for (int q = 0; q < 8; ++q) {
                acc[q] += bf2f(v0[q]) * n0 + bf2f(v1[q]) * n1
                        + bf2f(v2[q]) * n2 + bf2f(v3[q]) * n3;
            }
        }
        for (; j < rem; j += 4) {                // uniform bound
            int   je = j + grp;
            int   jc = min(je, rem - 1);         // clamp (rem >= 1 here)
            int   s  = __shfl(ev, jc);
            float nm = __shfl(nv, jc);
            if (je >= rem) nm = 0.f;             // data predication
            us8 v = *reinterpret_cast<const us8*>(hb + (size_t)s * OUT_F);
            #pragma unroll
            for (int q = 0; q < 8; ++q)
                acc[q] += bf2f(v[q]) * nm;
        }
    }

    // cross-group reduction: lanes gl, gl+16, gl+32, gl+48 hold partials of
    // the same 8 features
    #pragma unroll
    for (int q = 0; q < 8; ++q) {
        acc[q] += __shfl_xor(acc[q], 16);
        acc[q] += __shfl_xor(acc[q], 32);
    }

    if (grp == 0) {
        const float nd = norm[node];
        const float4 b0 = *reinterpret_cast<const float4*>(bias + gl * 8);
        const float4 b1 = *reinterpret_cast<const float4*>(bias + gl * 8 + 4);
        float4 r0, r1;
        r0.x = acc[0] * nd + b0.x;
        r0.y = acc[1] * nd + b0.y;
        r0.z = acc[2] * nd + b0.z;
        r0.w = acc[3] * nd + b0.w;
        r1.x = acc[4] * nd + b1.x;
        r1.y = acc[5] * nd + b1.y;
        r1.z = acc[6] * nd + b1.z;
        r1.w = acc[7] * nd + b1.w;
        float* o = out + (size_t)node * OUT_F + gl * 8;
        *reinterpret_cast<float4*>(o)     = r0;
        *reinterpret_cast<float4*>(o + 4) = r1;
    }
}

// ---------------------------------------------------------------------------
extern "C" void kernel_launch(void* const* d_in, const int* in_sizes, int n_in,
                              void* d_out, int out_size, void* d_ws, size_t ws_size,
                              hipStream_t stream) {
    const float* feat   = (const float*)d_in[0];
    const float* weight = (const float*)d_in[1];
    const float* bias   = (const float*)d_in[2];
    const int*   src    = (const int*)d_in[3];
    const int*   dst    = (const int*)d_in[4];
    float* out = (float*)d_out;

    const int n_nodes = in_sizes[0] / IN_F;
    const int n_edges = in_sizes[3];
    const int nbuck   = (n_nodes + BNODES - 1) >> BSH;
    const int gemm_blocks = (n_nodes + 255) / 256;

    char* ws = (char*)d_ws;
    size_t off = 0;
    auto alloc = [&](size_t bytes) {
        char* p = ws + off;
        off += (bytes + 15) & ~(size_t)15;
        return p;
    };
    unsigned short* h  = (unsigned short*)alloc((size_t)n_nodes * OUT_F * 2);
    float* norm        = (float*)alloc((size_t)n_nodes * 4);
    int*   rstart      = (int*)alloc(((size_t)n_nodes + 1) * 4);
    int*   bhist       = (int*)alloc(MAXBUCK * 4);
    int*   bstart      = (int*)alloc((MAXBUCK + 1) * 4);
    int*   gcur        = (int*)alloc(MAXBUCK * 4);
    unsigned short* Wt = (unsigned short*)alloc((size_t)OUT_F * IN_F * 2);
    unsigned* ebuf     = (unsigned*)alloc((size_t)n_edges * 4);
    int*   eidx        = (int*)alloc((size_t)n_edges * 4);

    hipMemsetAsync(bhist, 0, MAXBUCK * sizeof(int), stream);
    // K1: bin1a (blocks 0..255) || wprep (blocks 256..383)
    prep_kernel<<<BIN1A_BLOCKS + OUT_F, 256, 0, stream>>>(weight, Wt, dst, bhist,
                                                          n_edges, nbuck);
    // K2: bucket scan
    scanb_kernel<<<1, 1024, 0, stream>>>(bhist, bstart, gcur, rstart, nbuck, n_nodes);
    // K3: binning
    bin1b_kernel<<<BIN1B_BLOCKS, 256, 0, stream>>>(src, dst, gcur, ebuf, n_edges, nbuck);
    // K4: gemm (independent of bin chain; needs only Wt)
    gemm_mfma<<<gemm_blocks, 1024, 0, stream>>>(feat, Wt, h, n_nodes);
    // K5: exact CSR
    bin2_kernel<<<nbuck, 256, 0, stream>>>(ebuf, bstart, rstart, norm, eidx, n_nodes);
    // K6: aggregate
    agg_kernel<<<(n_nodes + 3) / 4, 256, 0, stream>>>(h, eidx, rstart, norm, bias, out, n_nodes);
}

// Round 15
// 146.334 us; speedup vs baseline: 1.0926x; 1.0677x over previous
//
#include <hip/hip_runtime.h>

#define IN_F 256
#define OUT_F 128
#define BSH 7
#define BNODES 128          // nodes per bucket = 1<<BSH
#define MAXBUCK 1024        // supports n_nodes <= 131072
#define BIN1A_BLOCKS 256
#define BIN1B_BLOCKS 256

typedef short bf16x8 __attribute__((ext_vector_type(8)));
typedef float f32x4 __attribute__((ext_vector_type(4)));
typedef unsigned short us8 __attribute__((ext_vector_type(8)));

__device__ inline unsigned short f2bf(float x) {
    union { float f; unsigned u; } v; v.f = x;
    unsigned r = v.u + 0x7FFFu + ((v.u >> 16) & 1u);   // round-nearest-even
    return (unsigned short)(r >> 16);
}
__device__ inline float bf2f(unsigned short x) {
    union { unsigned u; float f; } v; v.u = ((unsigned)x) << 16;
    return v.f;
}

// ---------------------------------------------------------------------------
// K1 fused: blocks [0, BIN1A_BLOCKS) = bin1a (bucket histogram -> bhist);
// blocks [BIN1A_BLOCKS, +128) = wprep (Wt = bf16(W^T)).
// bhist & gcur0 zeroed by hipMemsetAsync before this dispatch.
// ---------------------------------------------------------------------------
__global__ __launch_bounds__(256) void prep_kernel(const float* __restrict__ W,
                                                   unsigned short* __restrict__ Wt,
                                                   const int* __restrict__ dst,
                                                   int* __restrict__ bhist,
                                                   int n_edges, int nbuck) {
    if ((int)blockIdx.x < BIN1A_BLOCKS) {
        __shared__ int hist[MAXBUCK];
        const int tid = threadIdx.x;
        const int chunk = (n_edges + BIN1A_BLOCKS - 1) / BIN1A_BLOCKS;
        const int lo = blockIdx.x * chunk;
        const int hi = min(lo + chunk, n_edges);

        for (int i = tid; i < MAXBUCK; i += 256) hist[i] = 0;
        __syncthreads();
        for (int e = lo + tid; e < hi; e += 256)
            atomicAdd(&hist[dst[e] >> BSH], 1);
        __syncthreads();
        for (int i = tid; i < nbuck; i += 256) {
            int c = hist[i];
            if (c) atomicAdd(&bhist[i], c);
        }
    } else {
        int n = blockIdx.x - BIN1A_BLOCKS;   // 0..127
        int k = threadIdx.x;                 // 0..255
        Wt[n * IN_F + k] = f2bf(W[k * OUT_F + n]);
    }
}

// ---------------------------------------------------------------------------
// K2 fused (1024 threads): blocks [0, BIN1B_BLOCKS) = bin1b'; rest = gemm.
// bin1b': computes the bucket prefix LOCALLY from bhist (LDS scan — scanb
// kernel eliminated), reserves contiguous runs via gcur0 (zero-based cursor),
// then two-pass LDS-histogram places edges into bucket-grouped ebuf.
// gemm: 16 waves x 16 rows = 256 rows/blk, 64 KB swizzled Wt in LDS,
// 2 blocks/CU -> 8 waves/SIMD. LDS is a 64 KB union; a CU can co-host one
// gemm block + one bin block (128 KB LDS, 1280 thr) so bin1b hides under gemm.
// ---------------------------------------------------------------------------
__global__ __launch_bounds__(1024) void gemm_bin_kernel(
        const float* __restrict__ feat, const unsigned short* __restrict__ Wt,
        unsigned short* __restrict__ h, int n_nodes,
        const int* __restrict__ src, const int* __restrict__ dst,
        const int* __restrict__ bhist, int* __restrict__ gcur0,
        unsigned* __restrict__ ebuf, int n_edges, int nbuck) {

    __shared__ __align__(16) char smem[65536];

    if ((int)blockIdx.x < BIN1B_BLOCKS) {
        // ---------------- bin1b' ----------------
        int* scanv = (int*)smem;             // [MAXBUCK] bucket prefix
        int* hist  = scanv + MAXBUCK;        // [MAXBUCK]
        int* lbase = hist + MAXBUCK;         // [MAXBUCK]
        const int tid = threadIdx.x;
        const int chunk = (n_edges + BIN1B_BLOCKS - 1) / BIN1B_BLOCKS;
        const int lo = blockIdx.x * chunk;
        const int hi = min(lo + chunk, n_edges);

        // local exclusive scan of bhist (1024 wide, 1024 threads)
        int own = (tid < nbuck) ? bhist[tid] : 0;
        scanv[tid] = own;
        __syncthreads();
        #pragma unroll
        for (int off = 1; off < MAXBUCK; off <<= 1) {
            int t = (tid >= off) ? scanv[tid - off] : 0;
            __syncthreads();
            scanv[tid] += t;
            __syncthreads();
        }
        // scanv[tid] now inclusive; exclusive = inclusive - own
        int bstart_t = scanv[tid] - own;
        __syncthreads();
        scanv[tid] = bstart_t;               // reuse as exclusive bstart
        hist[tid] = 0;
        __syncthreads();

        for (int e = lo + tid; e < hi; e += 1024)
            atomicAdd(&hist[dst[e] >> BSH], 1);
        __syncthreads();
        if (tid < nbuck) {
            int c = hist[tid];
            lbase[tid] = (c > 0) ? (scanv[tid] + atomicAdd(&gcur0[tid], c)) : 0;
            hist[tid] = 0;                   // reuse as local cursor
        }
        __syncthreads();
        for (int e = lo + tid; e < hi; e += 1024) {
            int d = dst[e];
            int bkt = d >> BSH;
            int off = atomicAdd(&hist[bkt], 1);
            ebuf[lbase[bkt] + off] = ((unsigned)src[e] << BSH) | (unsigned)(d & (BNODES - 1));
        }
    } else {
        // ---------------- gemm ----------------
        unsigned short* Bs = (unsigned short*)smem;   // 64 KB, swizzled

        const int tid  = threadIdx.x;
        const int wave = tid >> 6;           // 0..15
        const int lane = tid & 63;
        const int gb   = blockIdx.x - BIN1B_BLOCKS;
        const int r0   = (gb * 16 + wave) * 16;
        const int lrow = lane & 15;
        const int g    = lane >> 4;          // k-group 0..3
        const int kgrp = g * 8;

        // stage Wt -> LDS (swizzled): 4096 x 16B chunks, 4 per thread
        {
            const f32x4* srcv = reinterpret_cast<const f32x4*>(Wt);
            f32x4* dstv = reinterpret_cast<f32x4*>(Bs);
            #pragma unroll
            for (int i = 0; i < 4; ++i) {
                int c   = tid + i * 1024;       // 16B-chunk index 0..4095
                int row = c >> 5;               // 0..127
                int col = c & 31;               // 16B unit within row
                dstv[c] = srcv[row * 32 + (col ^ (row & 7))];
            }
        }

        const int row  = r0 + lrow;
        const int rowc = (row < n_nodes) ? row : (n_nodes - 1);
        const float* arow = feat + (size_t)rowc * IN_F;

        __syncthreads();   // Bs ready

        f32x4 acc[8];
        #pragma unroll
        for (int n = 0; n < 8; ++n) acc[n] = (f32x4){0.f, 0.f, 0.f, 0.f};

        const bf16x8* bsv = reinterpret_cast<const bf16x8*>(Bs);

        #pragma unroll
        for (int k0 = 0; k0 < IN_F / 32; ++k0) {
            const f32x4 a0 = *reinterpret_cast<const f32x4*>(arow + k0 * 32 + kgrp);
            const f32x4 a1 = *reinterpret_cast<const f32x4*>(arow + k0 * 32 + kgrp + 4);
            bf16x8 afr;
            afr[0] = (short)f2bf(a0[0]);
            afr[1] = (short)f2bf(a0[1]);
            afr[2] = (short)f2bf(a0[2]);
            afr[3] = (short)f2bf(a0[3]);
            afr[4] = (short)f2bf(a1[0]);
            afr[5] = (short)f2bf(a1[1]);
            afr[6] = (short)f2bf(a1[2]);
            afr[7] = (short)f2bf(a1[3]);
            #pragma unroll
            for (int n = 0; n < 8; ++n) {
                const int brow = n * 16 + lrow;
                bf16x8 bfr = bsv[brow * 32 + ((k0 * 4 + g) ^ (brow & 7))];
                acc[n] = __builtin_amdgcn_mfma_f32_16x16x32_bf16(afr, bfr, acc[n], 0, 0, 0);
            }
        }

        const int orow0 = r0 + g * 4;
        #pragma unroll
        for (int n = 0; n < 8; ++n) {
            #pragma unroll
            for (int j = 0; j < 4; ++j) {
                int orow = orow0 + j;
                if (orow < n_nodes)
                    h[(size_t)orow * OUT_F + n * 16 + lrow] = f2bf(acc[n][j]);
            }
        }
    }
}

// ---------------------------------------------------------------------------
// bin2': one block per bucket. Recomputes bucket prefix locally from bhist
// (scanb eliminated), then per-node counts from ebuf (LDS), 128-wide scan ->
// rstart + norm, then exact per-node CSR placement. Bucket-local writes.
// ---------------------------------------------------------------------------
__global__ __launch_bounds__(256) void bin2_kernel(const unsigned* __restrict__ ebuf,
                                                   const int* __restrict__ bhist,
                                                   int* __restrict__ rstart,
                                                   float* __restrict__ norm,
                                                   int* __restrict__ eidx,
                                                   int n_nodes, int nbuck) {
    __shared__ int bs[MAXBUCK];          // bucket prefix scan
    __shared__ int lcnt[BNODES];
    __shared__ int lex[BNODES];
    const int tid = threadIdx.x;
    const int node0 = blockIdx.x << BSH;

    // local exclusive scan of bhist: 4 elems/thread, Hillis-Steele on sums
    {
        int v[4], s = 0;
        #pragma unroll
        for (int j = 0; j < 4; ++j) {
            int idx = tid * 4 + j;
            v[j] = (idx < nbuck) ? bhist[idx] : 0;
            s += v[j];
        }
        lexinit:;
        __shared__ int sh[256];
        sh[tid] = s;
        __syncthreads();
        #pragma unroll
        for (int off = 1; off < 256; off <<= 1) {
            int t = (tid >= off) ? sh[tid - off] : 0;
            __syncthreads();
            sh[tid] += t;
            __syncthreads();
        }
        int ex = sh[tid] - s;
        #pragma unroll
        for (int j = 0; j < 4; ++j) {
            bs[tid * 4 + j] = ex;
            ex += v[j];
        }
    }
    __syncthreads();

    const int e0 = bs[blockIdx.x];
    const int e1 = e0 + bhist[blockIdx.x];

    if (tid < BNODES) lcnt[tid] = 0;
    __syncthreads();
    for (int e = e0 + tid; e < e1; e += 256)
        atomicAdd(&lcnt[ebuf[e] & (BNODES - 1)], 1);
    __syncthreads();

    int own = (tid < BNODES) ? lcnt[tid] : 0;
    if (tid < BNODES) lex[tid] = own;
    __syncthreads();
    #pragma unroll
    for (int off = 1; off < BNODES; off <<= 1) {
        int t = (tid >= off && tid < BNODES) ? lex[tid - off] : 0;
        __syncthreads();
        if (tid < BNODES) lex[tid] += t;
        __syncthreads();
    }
    if (tid < BNODES) {
        int ex = lex[tid] - own;       // exclusive
        lex[tid] = ex;
        int g = node0 + tid;
        if (g <= n_nodes) rstart[g] = e0 + ex;   // includes global sentinel
        if (g < n_nodes) {
            float d = (float)own;
            if (d < 1.0f) d = 1.0f;
            norm[g] = 1.0f / sqrtf(d);
        }
        lcnt[tid] = 0;                 // reuse as cursor
    }
    __syncthreads();

    for (int e = e0 + tid; e < e1; e += 256) {
        unsigned pk = ebuf[e];
        int dl = pk & (BNODES - 1);
        int pos = atomicAdd(&lcnt[dl], 1);
        eidx[e0 + lex[dl] + pos] = (int)(pk >> BSH);
    }
}

// ---------------------------------------------------------------------------
// agg: one wave per dst node, 4 edge-slots x 16 lanes, UNIFORM control flow.
// (unchanged from round 13 — fabric-limited at ~65 us)
// ---------------------------------------------------------------------------
__global__ __launch_bounds__(256) void agg_kernel(const unsigned short* __restrict__ h,
                                                  const int* __restrict__ eidx,
                                                  const int* __restrict__ rstart,
                                                  const float* __restrict__ norm,
                                                  const float* __restrict__ bias,
                                                  float* __restrict__ out,
                                                  int n_nodes) {
    const int wave = threadIdx.x >> 6;
    const int lane = threadIdx.x & 63;
    const int grp  = lane >> 4;          // edge slot 0..3
    const int gl   = lane & 15;          // feature chunk
    const int node = blockIdx.x * 4 + wave;
    if (node >= n_nodes) return;         // wave-uniform; no barriers below

    const int start = rstart[node];
    const int cnt   = rstart[node + 1] - start;
    const unsigned short* __restrict__ hb = h + gl * 8;

    float acc[8] = {0.f, 0.f, 0.f, 0.f, 0.f, 0.f, 0.f, 0.f};

    for (int base = 0; base < cnt; base += 64) {
        const int rem = min(64, cnt - base);     // wave-uniform
        int   ev = (lane < rem) ? eidx[start + base + lane] : 0;
        float nv = (lane < rem) ? norm[ev] : 0.f;

        int j = 0;
        for (; j + 16 <= rem; j += 16) {         // uniform bound
            int   s0 = __shfl(ev, j + grp);
            int   s1 = __shfl(ev, j + grp + 4);
            int   s2 = __shfl(ev, j + grp + 8);
            int   s3 = __shfl(ev, j + grp + 12);
            float n0 = __shfl(nv, j + grp);
            float n1 = __shfl(nv, j + grp + 4);
            float n2 = __shfl(nv, j + grp + 8);
            float n3 = __shfl(nv, j + grp + 12);
            us8 v0 = *reinterpret_cast<const us8*>(hb + (size_t)s0 * OUT_F);
            us8 v1 = *reinterpret_cast<const us8*>(hb + (size_t)s1 * OUT_F);
            us8 v2 = *reinterpret_cast<const us8*>(hb + (size_t)s2 * OUT_F);
            us8 v3 = *reinterpret_cast<const us8*>(hb + (size_t)s3 * OUT_F);
            #pragma unroll
            for (int q = 0; q < 8; ++q) {
                acc[q] += bf2f(v0[q]) * n0 + bf2f(v1[q]) * n1
                        + bf2f(v2[q]) * n2 + bf2f(v3[q]) * n3;
            }
        }
        for (; j < rem; j += 4) {                // uniform bound
            int   je = j + grp;
            int   jc = min(je, rem - 1);         // clamp (rem >= 1 here)
            int   s  = __shfl(ev, jc);
            float nm = __shfl(nv, jc);
            if (je >= rem) nm = 0.f;             // data predication
            us8 v = *reinterpret_cast<const us8*>(hb + (size_t)s * OUT_F);
            #pragma unroll
            for (int q = 0; q < 8; ++q)
                acc[q] += bf2f(v[q]) * nm;
        }
    }

    #pragma unroll
    for (int q = 0; q < 8; ++q) {
        acc[q] += __shfl_xor(acc[q], 16);
        acc[q] += __shfl_xor(acc[q], 32);
    }

    if (grp == 0) {
        const float nd = norm[node];
        const float4 b0 = *reinterpret_cast<const float4*>(bias + gl * 8);
        const float4 b1 = *reinterpret_cast<const float4*>(bias + gl * 8 + 4);
        float4 r0, r1;
        r0.x = acc[0] * nd + b0.x;
        r0.y = acc[1] * nd + b0.y;
        r0.z = acc[2] * nd + b0.z;
        r0.w = acc[3] * nd + b0.w;
        r1.x = acc[4] * nd + b1.x;
        r1.y = acc[5] * nd + b1.y;
        r1.z = acc[6] * nd + b1.z;
        r1.w = acc[7] * nd + b1.w;
        float* o = out + (size_t)node * OUT_F + gl * 8;
        *reinterpret_cast<float4*>(o)     = r0;
        *reinterpret_cast<float4*>(o + 4) = r1;
    }
}

// ---------------------------------------------------------------------------
extern "C" void kernel_launch(void* const* d_in, const int* in_sizes, int n_in,
                              void* d_out, int out_size, void* d_ws, size_t ws_size,
                              hipStream_t stream) {
    const float* feat   = (const float*)d_in[0];
    const float* weight = (const float*)d_in[1];
    const float* bias   = (const float*)d_in[2];
    const int*   src    = (const int*)d_in[3];
    const int*   dst    = (const int*)d_in[4];
    float* out = (float*)d_out;

    const int n_nodes = in_sizes[0] / IN_F;
    const int n_edges = in_sizes[3];
    const int nbuck   = (n_nodes + BNODES - 1) >> BSH;
    const int gemm_blocks = (n_nodes + 255) / 256;

    char* ws = (char*)d_ws;
    size_t off = 0;
    auto alloc = [&](size_t bytes) {
        char* p = ws + off;
        off += (bytes + 15) & ~(size_t)15;
        return p;
    };
    unsigned short* h  = (unsigned short*)alloc((size_t)n_nodes * OUT_F * 2);
    float* norm        = (float*)alloc((size_t)n_nodes * 4);
    int*   rstart      = (int*)alloc(((size_t)n_nodes + 1) * 4);
    int*   bhist       = (int*)alloc(2 * MAXBUCK * 4);   // bhist | gcur0 (both zeroed)
    int*   gcur0       = bhist + MAXBUCK;
    unsigned short* Wt = (unsigned short*)alloc((size_t)OUT_F * IN_F * 2);
    unsigned* ebuf     = (unsigned*)alloc((size_t)n_edges * 4);
    int*   eidx        = (int*)alloc((size_t)n_edges * 4);

    hipMemsetAsync(bhist, 0, 2 * MAXBUCK * sizeof(int), stream);
    // K1: bin1a (blocks 0..255) || wprep (blocks 256..383)
    prep_kernel<<<BIN1A_BLOCKS + OUT_F, 256, 0, stream>>>(weight, Wt, dst, bhist,
                                                          n_edges, nbuck);
    // K2: bin1b' (blocks 0..255, local scan) || gemm (blocks 256..)
    gemm_bin_kernel<<<BIN1B_BLOCKS + gemm_blocks, 1024, 0, stream>>>(
        feat, Wt, h, n_nodes, src, dst, bhist, gcur0, ebuf, n_edges, nbuck);
    // K3: exact CSR (local scan)
    bin2_kernel<<<nbuck, 256, 0, stream>>>(ebuf, bhist, rstart, norm, eidx,
                                           n_nodes, nbuck);
    // K4: aggregate
    agg_kernel<<<(n_nodes + 3) / 4, 256, 0, stream>>>(h, eidx, rstart, norm, bias, out, n_nodes);
}